// Round 1
// baseline (264.798 us; speedup 1.0000x reference)
//
#include <hip/hip_runtime.h>

// ---------------- problem constants ----------------
#define MAX_IN   1024
#define MAX_OUT  4096
#define LOW_RANK 64
#define N_ARCH   16
#define HYP_HID  128
#define BATCH_M  8192   // 4 * 2048

typedef __attribute__((ext_vector_type(8))) short short8;   // 8 x bf16
typedef __attribute__((ext_vector_type(4))) float f32x4;

// round-to-nearest-even fp32 -> bf16
__device__ __forceinline__ unsigned short f2bf(float f) {
  union { float f; unsigned int u; } c; c.f = f;
  unsigned int r = c.u + 0x7fffu + ((c.u >> 16) & 1u);
  return (unsigned short)(r >> 16);
}

__device__ __forceinline__ void gload16(const unsigned short* g, unsigned short* l) {
  __builtin_amdgcn_global_load_lds(
      (const __attribute__((address_space(1))) unsigned int*)(g),
      (__attribute__((address_space(3))) unsigned int*)(l), 16, 0, 0);
}

// ---------------- kernel 1: hypernet layer 1 ----------------
__global__ void hyp_kernel(const float* __restrict__ w1, const float* __restrict__ b1,
                           const float* __restrict__ e, float* __restrict__ h) {
  int i = threadIdx.x;  // 128 threads
  float s = b1[i];
#pragma unroll
  for (int j = 0; j < N_ARCH; j++) s += w1[i * N_ARCH + j] * e[j];
  h[i] = fmaxf(s, 0.0f);
}

// ---------------- kernel 2: X fp32 -> bf16 ----------------
__global__ __launch_bounds__(256) void convert_x(const float* __restrict__ in,
                                                 unsigned short* __restrict__ out) {
  size_t i = (size_t)blockIdx.x * 256 + threadIdx.x;
  float4 v = *(const float4*)(in + i * 4);
  ushort4 o;
  o.x = f2bf(v.x); o.y = f2bf(v.y); o.z = f2bf(v.z); o.w = f2bf(v.w);
  *(ushort4*)(out + i * 4) = o;
}

// ---------------- kernel 3: build W (bf16) = base + left @ lr ----------------
// one block handles 8 output rows; 256 threads
__global__ __launch_bounds__(256) void build_weight(
    const float* __restrict__ hyp_w2, const float* __restrict__ hyp_b2,
    const float* __restrict__ h, const float* __restrict__ base_w,
    const float* __restrict__ lrf, unsigned short* __restrict__ Wbf) {
  __shared__ float left[8][LOW_RANK];
  __shared__ float hs[HYP_HID];
  const int tid = threadIdx.x;
  const int lane = tid & 63;
  const int wave = tid >> 6;
  if (tid < HYP_HID) hs[tid] = h[tid];
  __syncthreads();
  const int o0 = blockIdx.x * 8;

  // phase 1: left[oi][r] = hyp_w2[(o0+oi)*64+r, :] . h + b2
  for (int rr = wave; rr < 8 * LOW_RANK; rr += 4) {
    const float* row = hyp_w2 + (size_t)(o0 * LOW_RANK + rr) * HYP_HID;
    float2 v = *(const float2*)(row + lane * 2);
    float s = v.x * hs[lane * 2] + v.y * hs[lane * 2 + 1];
#pragma unroll
    for (int off = 32; off > 0; off >>= 1) s += __shfl_down(s, off);
    if (lane == 0) left[rr >> 6][rr & 63] = s + hyp_b2[o0 * LOW_RANK + rr];
  }
  __syncthreads();

  // phase 2: W[o0+oi][k] = base + sum_r left[oi][r] * lr[r][k]
#pragma unroll
  for (int kk = 0; kk < 4; kk++) {
    const int k = kk * 256 + tid;
    float acc[8];
#pragma unroll
    for (int oi = 0; oi < 8; oi++) acc[oi] = base_w[(size_t)(o0 + oi) * MAX_IN + k];
    for (int r = 0; r < LOW_RANK; r++) {
      float lv = lrf[r * MAX_IN + k];
#pragma unroll
      for (int oi = 0; oi < 8; oi++) acc[oi] += left[oi][r] * lv;
    }
#pragma unroll
    for (int oi = 0; oi < 8; oi++)
      Wbf[(size_t)(o0 + oi) * MAX_IN + k] = f2bf(acc[oi]);
  }
}

// ---------------- kernel 4: GEMM  C = Xbf @ Wbf^T + bias ----------------
// 128x128 tile, BK=32, 4 waves (2x2), each wave 64x64 via 4x4 frags of 16x16x32
__global__ __launch_bounds__(256) void gemm_kernel(
    const unsigned short* __restrict__ A,   // [M][K] bf16
    const unsigned short* __restrict__ B,   // [N][K] bf16 (= W, already B^T layout)
    const float* __restrict__ bias,         // [N]
    float* __restrict__ C) {                // [M][N] fp32
  constexpr int K = MAX_IN;
  constexpr int N = MAX_OUT;
  __shared__ __align__(16) unsigned short sA[128 * 32];
  __shared__ __align__(16) unsigned short sB[128 * 32];
  const int tid = threadIdx.x;
  const int lane = tid & 63;
  const int wave = tid >> 6;
  const int wr = wave >> 1;
  const int wc = wave & 1;
  const int bm = blockIdx.y * 128;
  const int bn = blockIdx.x * 128;
  const int r0 = tid >> 2;          // staging row 0..63
  const int c0 = (tid & 3) * 8;     // staging col {0,8,16,24}
  const int fl = lane & 15;         // fragment row/col
  const int lk = (lane >> 4) * 8;   // fragment k offset

  f32x4 acc[4][4];
#pragma unroll
  for (int m = 0; m < 4; m++)
#pragma unroll
    for (int n = 0; n < 4; n++) acc[m][n] = (f32x4){0.f, 0.f, 0.f, 0.f};

  const unsigned short* Ab = A + (size_t)bm * K;
  const unsigned short* Bb = B + (size_t)bn * K;

  for (int k0 = 0; k0 < K; k0 += 32) {
#pragma unroll
    for (int i = 0; i < 2; i++) {
      gload16(Ab + (size_t)(i * 64 + r0) * K + k0 + c0, &sA[(i * 64 + r0) * 32 + c0]);
      gload16(Bb + (size_t)(i * 64 + r0) * K + k0 + c0, &sB[(i * 64 + r0) * 32 + c0]);
    }
    __syncthreads();
    short8 a[4], b[4];
#pragma unroll
    for (int m = 0; m < 4; m++)
      a[m] = *(const short8*)&sA[(wr * 64 + m * 16 + fl) * 32 + lk];
#pragma unroll
    for (int n = 0; n < 4; n++)
      b[n] = *(const short8*)&sB[(wc * 64 + n * 16 + fl) * 32 + lk];
#pragma unroll
    for (int m = 0; m < 4; m++)
#pragma unroll
      for (int n = 0; n < 4; n++)
        acc[m][n] = __builtin_amdgcn_mfma_f32_16x16x32_bf16(a[m], b[n], acc[m][n], 0, 0, 0);
    __syncthreads();
  }

  // epilogue: C/D layout col=lane&15, row=(lane>>4)*4+j
  const int col_l = lane & 15;
  const int row_l = (lane >> 4) * 4;
#pragma unroll
  for (int m = 0; m < 4; m++) {
#pragma unroll
    for (int n = 0; n < 4; n++) {
      const int gr = bm + wr * 64 + m * 16 + row_l;
      const int gc = bn + wc * 64 + n * 16 + col_l;
      const float bv = bias[gc];
#pragma unroll
      for (int j = 0; j < 4; j++)
        C[(size_t)(gr + j) * N + gc] = acc[m][n][j] + bv;
    }
  }
}

// ---------------- launcher ----------------
extern "C" void kernel_launch(void* const* d_in, const int* in_sizes, int n_in,
                              void* d_out, int out_size, void* d_ws, size_t ws_size,
                              hipStream_t stream) {
  const float* x      = (const float*)d_in[0];
  const float* embed  = (const float*)d_in[1];
  const float* base_w = (const float*)d_in[2];
  const float* base_b = (const float*)d_in[3];
  const float* lrf    = (const float*)d_in[4];
  const float* w1     = (const float*)d_in[5];
  const float* b1     = (const float*)d_in[6];
  const float* w2     = (const float*)d_in[7];
  const float* b2     = (const float*)d_in[8];
  float* out = (float*)d_out;

  char* ws = (char*)d_ws;
  float* h = (float*)ws;                                        // 512 B
  unsigned short* Xbf = (unsigned short*)(ws + 1024);           // 16 MB
  unsigned short* Wbf = (unsigned short*)(ws + 1024 + (size_t)BATCH_M * MAX_IN * 2);  // 8 MB

  hipLaunchKernelGGL(hyp_kernel, dim3(1), dim3(HYP_HID), 0, stream, w1, b1, embed, h);
  hipLaunchKernelGGL(convert_x, dim3(BATCH_M * MAX_IN / 1024), dim3(256), 0, stream, x, Xbf);
  hipLaunchKernelGGL(build_weight, dim3(MAX_OUT / 8), dim3(256), 0, stream,
                     w2, b2, h, base_w, lrf, Wbf);
  hipLaunchKernelGGL(gemm_kernel, dim3(MAX_OUT / 128, BATCH_M / 128), dim3(256), 0, stream,
                     Xbf, Wbf, base_b, out);
}

// Round 3
// 173.384 us; speedup vs baseline: 1.5272x; 1.5272x over previous
//
#include <hip/hip_runtime.h>

// ---------------- problem constants ----------------
#define MAX_IN   1024
#define MAX_OUT  4096
#define LOW_RANK 64
#define N_ARCH   16
#define HYP_HID  128
#define BATCH_M  8192   // 4 * 2048

typedef __attribute__((ext_vector_type(8))) short short8;   // 8 x bf16
typedef __attribute__((ext_vector_type(4))) float f32x4;

// round-to-nearest-even fp32 -> bf16
__device__ __forceinline__ unsigned short f2bf(float f) {
  union { float f; unsigned int u; } c; c.f = f;
  unsigned int r = c.u + 0x7fffu + ((c.u >> 16) & 1u);
  return (unsigned short)(r >> 16);
}

__device__ __forceinline__ void gload16(const unsigned short* g, unsigned short* l) {
  __builtin_amdgcn_global_load_lds(
      (const __attribute__((address_space(1))) unsigned int*)(g),
      (__attribute__((address_space(3))) unsigned int*)(l), 16, 0, 0);
}

// ---------------- kernel 1: hypernet layer 1 ----------------
__global__ void hyp_kernel(const float* __restrict__ w1, const float* __restrict__ b1,
                           const float* __restrict__ e, float* __restrict__ h) {
  int i = threadIdx.x;  // 128 threads
  float s = b1[i];
#pragma unroll
  for (int j = 0; j < N_ARCH; j++) s += w1[i * N_ARCH + j] * e[j];
  h[i] = fmaxf(s, 0.0f);
}

// ---------------- kernel 2: X fp32 -> bf16 ----------------
__global__ __launch_bounds__(256) void convert_x(const float* __restrict__ in,
                                                 unsigned short* __restrict__ out) {
  size_t i = (size_t)blockIdx.x * 256 + threadIdx.x;
  float4 v = *(const float4*)(in + i * 4);
  ushort4 o;
  o.x = f2bf(v.x); o.y = f2bf(v.y); o.z = f2bf(v.z); o.w = f2bf(v.w);
  *(ushort4*)(out + i * 4) = o;
}

// ---------------- kernel 3a: left = hyp_w2 @ h + b2  (BW-bound matvec) ----------------
// 8 lanes per row: each group of 8 lanes reads 128B contiguous per load.
// 32 rows per wave; 2048 blocks x 4 waves = 8192 waves cover 262144 rows.
__global__ __launch_bounds__(256) void build_left(
    const float* __restrict__ hyp_w2, const float* __restrict__ hyp_b2,
    const float* __restrict__ h, float* __restrict__ left) {
  const int tid = threadIdx.x;
  const int lane = tid & 63;
  const int g = lane >> 3;      // group 0..7 (row within 8-row pack)
  const int gl = lane & 7;      // lane within group
  // this lane's h fragment: cols chunk*32 + gl*4, chunk = 0..3
  float4 hf[4];
#pragma unroll
  for (int c = 0; c < 4; c++)
    hf[c] = *(const float4*)(h + c * 32 + gl * 4);
  const int wid = blockIdx.x * 4 + (tid >> 6);   // global wave id [0, 8192)
  const int row0 = wid * 32;
#pragma unroll
  for (int it = 0; it < 4; it++) {
    const int row = row0 + it * 8 + g;
    const float* rp = hyp_w2 + (size_t)row * HYP_HID;
    float s = 0.f;
#pragma unroll
    for (int c = 0; c < 4; c++) {
      float4 v = *(const float4*)(rp + c * 32 + gl * 4);
      s += v.x * hf[c].x + v.y * hf[c].y + v.z * hf[c].z + v.w * hf[c].w;
    }
    s += __shfl_xor(s, 4);
    s += __shfl_xor(s, 2);
    s += __shfl_xor(s, 1);
    if (gl == 0) left[row] = s + hyp_b2[row];
  }
}

// ---------------- kernel 3b: W (bf16) = base + left @ lr ----------------
// one block handles 8 output rows; 256 threads
__global__ __launch_bounds__(256) void build_w(
    const float* __restrict__ left, const float* __restrict__ base_w,
    const float* __restrict__ lrf, unsigned short* __restrict__ Wbf) {
  __shared__ float lefts[8][LOW_RANK];
  const int tid = threadIdx.x;
  const int o0 = blockIdx.x * 8;
#pragma unroll
  for (int i = tid; i < 8 * LOW_RANK; i += 256)
    ((float*)lefts)[i] = left[o0 * LOW_RANK + i];
  __syncthreads();

#pragma unroll
  for (int kk = 0; kk < 4; kk++) {
    const int k = kk * 256 + tid;
    float acc[8];
#pragma unroll
    for (int oi = 0; oi < 8; oi++) acc[oi] = base_w[(size_t)(o0 + oi) * MAX_IN + k];
    for (int r = 0; r < LOW_RANK; r++) {
      float lv = lrf[r * MAX_IN + k];
#pragma unroll
      for (int oi = 0; oi < 8; oi++) acc[oi] += lefts[oi][r] * lv;
    }
#pragma unroll
    for (int oi = 0; oi < 8; oi++)
      Wbf[(size_t)(o0 + oi) * MAX_IN + k] = f2bf(acc[oi]);
  }
}

// ---------------- kernel 4: GEMM  C = Xbf @ Wbf^T + bias ----------------
// 128x128 tile, BK=32, 4 waves (2x2), each wave 64x64 via 4x4 frags of 16x16x32
__global__ __launch_bounds__(256) void gemm_kernel(
    const unsigned short* __restrict__ A,   // [M][K] bf16
    const unsigned short* __restrict__ B,   // [N][K] bf16 (= W, already B^T layout)
    const float* __restrict__ bias,         // [N]
    float* __restrict__ C) {                // [M][N] fp32
  constexpr int K = MAX_IN;
  constexpr int N = MAX_OUT;
  __shared__ __align__(16) unsigned short sA[128 * 32];
  __shared__ __align__(16) unsigned short sB[128 * 32];
  const int tid = threadIdx.x;
  const int lane = tid & 63;
  const int wave = tid >> 6;
  const int wr = wave >> 1;
  const int wc = wave & 1;

  // XCD-aware bijective swizzle: nwg = 2048, divisible by 8.
  const int orig = blockIdx.y * gridDim.x + blockIdx.x;       // [0, 2048)
  const int wg = (orig & 7) * 256 + (orig >> 3);
  const int bm = (wg >> 5) * 128;   // 64 M-tiles
  const int bn = (wg & 31) * 128;   // 32 N-tiles

  const int r0 = tid >> 2;          // staging row 0..63
  const int c0 = (tid & 3) * 8;     // staging col {0,8,16,24}
  const int fl = lane & 15;         // fragment row/col
  const int lk = (lane >> 4) * 8;   // fragment k offset

  f32x4 acc[4][4];
#pragma unroll
  for (int m = 0; m < 4; m++)
#pragma unroll
    for (int n = 0; n < 4; n++) acc[m][n] = (f32x4){0.f, 0.f, 0.f, 0.f};

  const unsigned short* Ab = A + (size_t)bm * K;
  const unsigned short* Bb = B + (size_t)bn * K;

  for (int k0 = 0; k0 < K; k0 += 32) {
#pragma unroll
    for (int i = 0; i < 2; i++) {
      gload16(Ab + (size_t)(i * 64 + r0) * K + k0 + c0, &sA[(i * 64 + r0) * 32 + c0]);
      gload16(Bb + (size_t)(i * 64 + r0) * K + k0 + c0, &sB[(i * 64 + r0) * 32 + c0]);
    }
    __syncthreads();
    short8 a[4], b[4];
#pragma unroll
    for (int m = 0; m < 4; m++)
      a[m] = *(const short8*)&sA[(wr * 64 + m * 16 + fl) * 32 + lk];
#pragma unroll
    for (int n = 0; n < 4; n++)
      b[n] = *(const short8*)&sB[(wc * 64 + n * 16 + fl) * 32 + lk];
#pragma unroll
    for (int m = 0; m < 4; m++)
#pragma unroll
      for (int n = 0; n < 4; n++)
        acc[m][n] = __builtin_amdgcn_mfma_f32_16x16x32_bf16(a[m], b[n], acc[m][n], 0, 0, 0);
    __syncthreads();
  }

  // epilogue: C/D layout col=lane&15, row=(lane>>4)*4+j
  const int col_l = lane & 15;
  const int row_l = (lane >> 4) * 4;
#pragma unroll
  for (int m = 0; m < 4; m++) {
#pragma unroll
    for (int n = 0; n < 4; n++) {
      const int gr = bm + wr * 64 + m * 16 + row_l;
      const int gc = bn + wc * 64 + n * 16 + col_l;
      const float bv = bias[gc];
#pragma unroll
      for (int j = 0; j < 4; j++)
        C[(size_t)(gr + j) * N + gc] = acc[m][n][j] + bv;
    }
  }
}

// ---------------- launcher ----------------
extern "C" void kernel_launch(void* const* d_in, const int* in_sizes, int n_in,
                              void* d_out, int out_size, void* d_ws, size_t ws_size,
                              hipStream_t stream) {
  const float* x      = (const float*)d_in[0];
  const float* embed  = (const float*)d_in[1];
  const float* base_w = (const float*)d_in[2];
  const float* base_b = (const float*)d_in[3];
  const float* lrf    = (const float*)d_in[4];
  const float* w1     = (const float*)d_in[5];
  const float* b1     = (const float*)d_in[6];
  const float* w2     = (const float*)d_in[7];
  const float* b2     = (const float*)d_in[8];
  float* out = (float*)d_out;

  char* ws = (char*)d_ws;
  float* h = (float*)ws;                                                  // 512 B
  unsigned short* Xbf = (unsigned short*)(ws + 1024);                     // 16 MB
  size_t off_w = 1024 + (size_t)BATCH_M * MAX_IN * 2;
  unsigned short* Wbf = (unsigned short*)(ws + off_w);                    // 8 MB
  size_t off_left = off_w + (size_t)MAX_OUT * MAX_IN * 2;
  size_t need = off_left + (size_t)MAX_OUT * LOW_RANK * 4;                // +1 MB
  // left scratch: ws if it fits, else the tail of d_out (gemm overwrites it later)
  float* left = (ws_size >= need)
      ? (float*)(ws + off_left)
      : out + ((size_t)BATCH_M * MAX_OUT - (size_t)MAX_OUT * LOW_RANK);

  hipLaunchKernelGGL(hyp_kernel, dim3(1), dim3(HYP_HID), 0, stream, w1, b1, embed, h);
  hipLaunchKernelGGL(convert_x, dim3(BATCH_M * MAX_IN / 1024), dim3(256), 0, stream, x, Xbf);
  // 262144 rows, 128 rows per block (4 waves x 32 rows) -> 2048 blocks
  hipLaunchKernelGGL(build_left, dim3(MAX_OUT * LOW_RANK / 128), dim3(256), 0, stream,
                     w2, b2, h, left);
  hipLaunchKernelGGL(build_w, dim3(MAX_OUT / 8), dim3(256), 0, stream,
                     left, base_w, lrf, Wbf);
  hipLaunchKernelGGL(gemm_kernel, dim3(MAX_OUT / 128, BATCH_M / 128), dim3(256), 0, stream,
                     Xbf, Wbf, base_b, out);
}

// Round 4
// 160.522 us; speedup vs baseline: 1.6496x; 1.0801x over previous
//
#include <hip/hip_runtime.h>

// ---------------- problem constants ----------------
#define MAX_IN   1024
#define MAX_OUT  4096
#define LOW_RANK 64
#define N_ARCH   16
#define HYP_HID  128
#define BATCH_M  8192   // 4 * 2048

typedef __attribute__((ext_vector_type(8))) short short8;   // 8 x bf16
typedef __attribute__((ext_vector_type(4))) float f32x4;

// round-to-nearest-even fp32 -> bf16
__device__ __forceinline__ unsigned short f2bf(float f) {
  union { float f; unsigned int u; } c; c.f = f;
  unsigned int r = c.u + 0x7fffu + ((c.u >> 16) & 1u);
  return (unsigned short)(r >> 16);
}

__device__ __forceinline__ void gload16(const unsigned short* g, unsigned short* l) {
  __builtin_amdgcn_global_load_lds(
      (const __attribute__((address_space(1))) unsigned int*)(g),
      (__attribute__((address_space(3))) unsigned int*)(l), 16, 0, 0);
}

// ---------------- kernel 1: hypernet layer 1 ----------------
__global__ void hyp_kernel(const float* __restrict__ w1, const float* __restrict__ b1,
                           const float* __restrict__ e, float* __restrict__ h) {
  int i = threadIdx.x;  // 128 threads
  float s = b1[i];
#pragma unroll
  for (int j = 0; j < N_ARCH; j++) s += w1[i * N_ARCH + j] * e[j];
  h[i] = fmaxf(s, 0.0f);
}

// ---------------- kernel 2: X fp32 -> bf16 ----------------
__global__ __launch_bounds__(256) void convert_x(const float* __restrict__ in,
                                                 unsigned short* __restrict__ out) {
  size_t i = (size_t)blockIdx.x * 256 + threadIdx.x;
  float4 v = *(const float4*)(in + i * 4);
  ushort4 o;
  o.x = f2bf(v.x); o.y = f2bf(v.y); o.z = f2bf(v.z); o.w = f2bf(v.w);
  *(ushort4*)(out + i * 4) = o;
}

// ---------------- kernel 3a: left = hyp_w2 @ h + b2  (BW-bound matvec) ----------------
__global__ __launch_bounds__(256) void build_left(
    const float* __restrict__ hyp_w2, const float* __restrict__ hyp_b2,
    const float* __restrict__ h, float* __restrict__ left) {
  const int tid = threadIdx.x;
  const int lane = tid & 63;
  const int g = lane >> 3;      // group 0..7 (row within 8-row pack)
  const int gl = lane & 7;      // lane within group
  float4 hf[4];
#pragma unroll
  for (int c = 0; c < 4; c++)
    hf[c] = *(const float4*)(h + c * 32 + gl * 4);
  const int wid = blockIdx.x * 4 + (tid >> 6);   // global wave id [0, 8192)
  const int row0 = wid * 32;
#pragma unroll
  for (int it = 0; it < 4; it++) {
    const int row = row0 + it * 8 + g;
    const float* rp = hyp_w2 + (size_t)row * HYP_HID;
    float s = 0.f;
#pragma unroll
    for (int c = 0; c < 4; c++) {
      float4 v = *(const float4*)(rp + c * 32 + gl * 4);
      s += v.x * hf[c].x + v.y * hf[c].y + v.z * hf[c].z + v.w * hf[c].w;
    }
    s += __shfl_xor(s, 4);
    s += __shfl_xor(s, 2);
    s += __shfl_xor(s, 1);
    if (gl == 0) left[row] = s + hyp_b2[row];
  }
}

// ---------------- kernel 3b: W (bf16) = base + left @ lr ----------------
__global__ __launch_bounds__(256) void build_w(
    const float* __restrict__ left, const float* __restrict__ base_w,
    const float* __restrict__ lrf, unsigned short* __restrict__ Wbf) {
  __shared__ float lefts[8][LOW_RANK];
  const int tid = threadIdx.x;
  const int o0 = blockIdx.x * 8;
#pragma unroll
  for (int i = tid; i < 8 * LOW_RANK; i += 256)
    ((float*)lefts)[i] = left[o0 * LOW_RANK + i];
  __syncthreads();

#pragma unroll
  for (int kk = 0; kk < 4; kk++) {
    const int k = kk * 256 + tid;
    float acc[8];
#pragma unroll
    for (int oi = 0; oi < 8; oi++) acc[oi] = base_w[(size_t)(o0 + oi) * MAX_IN + k];
    for (int r = 0; r < LOW_RANK; r++) {
      float lv = lrf[r * MAX_IN + k];
#pragma unroll
      for (int oi = 0; oi < 8; oi++) acc[oi] += lefts[oi][r] * lv;
    }
#pragma unroll
    for (int oi = 0; oi < 8; oi++)
      Wbf[(size_t)(o0 + oi) * MAX_IN + k] = f2bf(acc[oi]);
  }
}

// ---------------- kernel 4: pipelined GEMM  C = Xbf @ Wbf^T + bias ----------------
// 128x256 tile, BK=32, 4 waves (2M x 2N), wave-tile 64x128 (4x8 frags of 16x16x32).
// 3 LDS buffers (72 KB), prefetch distance 2, counted vmcnt(6), raw s_barrier.
// LDS swizzle: element (r, c16) at byte (r>>1)*128 + (r&1)*64 + ((c^((r>>1)&3))*16);
// staged via pre-swizzled GLOBAL source + linear gload_lds dest; read with same XOR.
__global__ __launch_bounds__(256, 2) void gemm_kernel(
    const unsigned short* __restrict__ A,   // [M][K] bf16
    const unsigned short* __restrict__ B,   // [N][K] bf16 (= W)
    const float* __restrict__ bias,         // [N]
    float* __restrict__ C) {                // [M][N] fp32
  constexpr int K = MAX_IN;
  constexpr int N = MAX_OUT;
  constexpr int ABUF = 128 * 32;           // 4096 ushorts = 8 KB
  constexpr int BBUF = 256 * 32;           // 8192 ushorts = 16 KB
  constexpr int TBUF = ABUF + BBUF;        // 12288 ushorts
  constexpr int NT = K / 32;               // 32 K-tiles
  __shared__ __align__(16) unsigned short lds[3 * TBUF];  // 72 KB

  const int tid = threadIdx.x;
  const int lane = tid & 63;
  const int w = tid >> 6;                  // wave 0..3
  const int wm = w >> 1, wn = w & 1;
  const int fl = lane & 15, hi = lane >> 4;

  // XCD-aware swizzle: 1024 wgs, 128 contiguous per XCD
  const int orig = blockIdx.x;
  const int wg = (orig & 7) * 128 + (orig >> 3);
  const int bm = (wg >> 4) * 128;          // 64 M-tiles
  const int bn = (wg & 15) * 256;          // 16 N-tiles

  // ---- staging coords: slot s holds element (r = s>>2, c = (s&3)^((s>>3)&3)) ----
  const int sA0 = w * 128 + lane;          // + 64*j, j=0..1
  const int rA = sA0 >> 2;
  const int cA = (sA0 & 3) ^ ((sA0 >> 3) & 3);
  const int sB0 = w * 256 + lane;          // + 64*j, j=0..3
  const int rB = sB0 >> 2;
  const int cB = (sB0 & 3) ^ ((sB0 >> 3) & 3);
  const unsigned short* Ag = A + (size_t)(bm + rA) * K + cA * 8;
  const unsigned short* Bg = B + (size_t)(bn + rB) * K + cB * 8;

  // ---- fragment read bases (ushort offsets inside a tile buffer) ----
  const int swz = hi ^ ((fl >> 1) & 3);
  const int abase = (wm * 32 + (fl >> 1)) * 64 + (fl & 1) * 32 + swz * 8;
  const int bbase = (wn * 64 + (fl >> 1)) * 64 + (fl & 1) * 32 + swz * 8;

  f32x4 acc[4][8];
#pragma unroll
  for (int m = 0; m < 4; m++)
#pragma unroll
    for (int n = 0; n < 8; n++) acc[m][n] = (f32x4){0.f, 0.f, 0.f, 0.f};

#define STAGE(p, t)                                                            \
  do {                                                                         \
    unsigned short* la_ = &lds[(p) * TBUF];                                    \
    unsigned short* lb_ = la_ + ABUF;                                          \
    _Pragma("unroll")                                                          \
    for (int j = 0; j < 2; j++)                                                \
      gload16(Ag + (size_t)(16 * j) * K + (t) * 32, &la_[(sA0 + 64 * j) * 8]); \
    _Pragma("unroll")                                                          \
    for (int j = 0; j < 4; j++)                                                \
      gload16(Bg + (size_t)(16 * j) * K + (t) * 32, &lb_[(sB0 + 64 * j) * 8]); \
  } while (0)

  // prologue: tiles 0,1 in flight; wait tile 0 (allow tile 1's 6 loads)
  STAGE(0, 0);
  STAGE(1, 1);
  asm volatile("s_waitcnt vmcnt(6)" ::: "memory");
  __builtin_amdgcn_s_barrier();
  __builtin_amdgcn_sched_barrier(0);

  int p = 0;
  for (int t = 0; t < NT; ++t) {
    if (t + 2 < NT) {
      const int pn = (p + 2 >= 3) ? p - 1 : p + 2;
      STAGE(pn, t + 2);
    }
    const unsigned short* la = &lds[p * TBUF];
    const unsigned short* lb = la + ABUF;
    short8 a[4], b[8];
#pragma unroll
    for (int m = 0; m < 4; m++) a[m] = *(const short8*)&la[abase + m * 512];
#pragma unroll
    for (int n = 0; n < 8; n++) b[n] = *(const short8*)&lb[bbase + n * 512];
    __builtin_amdgcn_s_setprio(1);
#pragma unroll
    for (int m = 0; m < 4; m++)
#pragma unroll
      for (int n = 0; n < 8; n++)
        acc[m][n] = __builtin_amdgcn_mfma_f32_16x16x32_bf16(a[m], b[n], acc[m][n], 0, 0, 0);
    __builtin_amdgcn_s_setprio(0);
    if (t + 2 < NT) {
      asm volatile("s_waitcnt vmcnt(6)" ::: "memory");   // tile t+1 landed
    } else if (t + 2 == NT) {
      asm volatile("s_waitcnt vmcnt(0)" ::: "memory");   // final tile landed
    }
    if (t + 1 < NT) {
      __builtin_amdgcn_s_barrier();
      __builtin_amdgcn_sched_barrier(0);
    }
    p = (p + 1 == 3) ? 0 : p + 1;
  }
#undef STAGE

  // ---- epilogue: C/D layout col=lane&15, row=(lane>>4)*4+j ----
  float bv[8];
#pragma unroll
  for (int n = 0; n < 8; n++) bv[n] = bias[bn + wn * 128 + n * 16 + fl];
#pragma unroll
  for (int m = 0; m < 4; m++) {
    const int gr0 = bm + wm * 64 + m * 16 + hi * 4;
#pragma unroll
    for (int n = 0; n < 8; n++) {
      const int gc = bn + wn * 128 + n * 16 + fl;
#pragma unroll
      for (int j = 0; j < 4; j++)
        C[(size_t)(gr0 + j) * N + gc] = acc[m][n][j] + bv[n];
    }
  }
}

// ---------------- launcher ----------------
extern "C" void kernel_launch(void* const* d_in, const int* in_sizes, int n_in,
                              void* d_out, int out_size, void* d_ws, size_t ws_size,
                              hipStream_t stream) {
  const float* x      = (const float*)d_in[0];
  const float* embed  = (const float*)d_in[1];
  const float* base_w = (const float*)d_in[2];
  const float* base_b = (const float*)d_in[3];
  const float* lrf    = (const float*)d_in[4];
  const float* w1     = (const float*)d_in[5];
  const float* b1     = (const float*)d_in[6];
  const float* w2     = (const float*)d_in[7];
  const float* b2     = (const float*)d_in[8];
  float* out = (float*)d_out;

  char* ws = (char*)d_ws;
  float* h = (float*)ws;                                                  // 512 B
  unsigned short* Xbf = (unsigned short*)(ws + 1024);                     // 16 MB
  size_t off_w = 1024 + (size_t)BATCH_M * MAX_IN * 2;
  unsigned short* Wbf = (unsigned short*)(ws + off_w);                    // 8 MB
  size_t off_left = off_w + (size_t)MAX_OUT * MAX_IN * 2;
  size_t need = off_left + (size_t)MAX_OUT * LOW_RANK * 4;                // +1 MB
  float* left = (ws_size >= need)
      ? (float*)(ws + off_left)
      : out + ((size_t)BATCH_M * MAX_OUT - (size_t)MAX_OUT * LOW_RANK);

  hipLaunchKernelGGL(hyp_kernel, dim3(1), dim3(HYP_HID), 0, stream, w1, b1, embed, h);
  hipLaunchKernelGGL(convert_x, dim3(BATCH_M * MAX_IN / 1024), dim3(256), 0, stream, x, Xbf);
  hipLaunchKernelGGL(build_left, dim3(MAX_OUT * LOW_RANK / 128), dim3(256), 0, stream,
                     w2, b2, h, left);
  hipLaunchKernelGGL(build_w, dim3(MAX_OUT / 8), dim3(256), 0, stream,
                     left, base_w, lrf, Wbf);
  hipLaunchKernelGGL(gemm_kernel, dim3((BATCH_M / 128) * (MAX_OUT / 256)), dim3(256), 0, stream,
                     Xbf, Wbf, base_b, out);
}

// Round 5
// 159.021 us; speedup vs baseline: 1.6652x; 1.0094x over previous
//
#include <hip/hip_runtime.h>

// ---------------- problem constants ----------------
#define MAX_IN   1024
#define MAX_OUT  4096
#define LOW_RANK 64
#define N_ARCH   16
#define HYP_HID  128
#define BATCH_M  8192   // 4 * 2048

typedef __attribute__((ext_vector_type(8))) short short8;   // 8 x bf16
typedef __attribute__((ext_vector_type(4))) float f32x4;

// round-to-nearest-even fp32 -> bf16
__device__ __forceinline__ unsigned short f2bf(float f) {
  union { float f; unsigned int u; } c; c.f = f;
  unsigned int r = c.u + 0x7fffu + ((c.u >> 16) & 1u);
  return (unsigned short)(r >> 16);
}

__device__ __forceinline__ void gload16(const unsigned short* g, unsigned short* l) {
  __builtin_amdgcn_global_load_lds(
      (const __attribute__((address_space(1))) unsigned int*)(g),
      (__attribute__((address_space(3))) unsigned int*)(l), 16, 0, 0);
}

// ---------------- kernel 1: hypernet layer 1 ----------------
__global__ void hyp_kernel(const float* __restrict__ w1, const float* __restrict__ b1,
                           const float* __restrict__ e, float* __restrict__ h) {
  int i = threadIdx.x;  // 128 threads
  float s = b1[i];
#pragma unroll
  for (int j = 0; j < N_ARCH; j++) s += w1[i * N_ARCH + j] * e[j];
  h[i] = fmaxf(s, 0.0f);
}

// ---------------- kernel 2: X fp32 -> bf16 ----------------
__global__ __launch_bounds__(256) void convert_x(const float* __restrict__ in,
                                                 unsigned short* __restrict__ out) {
  size_t i = (size_t)blockIdx.x * 256 + threadIdx.x;
  float4 v = *(const float4*)(in + i * 4);
  ushort4 o;
  o.x = f2bf(v.x); o.y = f2bf(v.y); o.z = f2bf(v.z); o.w = f2bf(v.w);
  *(ushort4*)(out + i * 4) = o;
}

// ---------------- kernel 3a: left = hyp_w2 @ h + b2  (BW-bound matvec) ----------------
__global__ __launch_bounds__(256) void build_left(
    const float* __restrict__ hyp_w2, const float* __restrict__ hyp_b2,
    const float* __restrict__ h, float* __restrict__ left) {
  const int tid = threadIdx.x;
  const int lane = tid & 63;
  const int g = lane >> 3;      // group 0..7 (row within 8-row pack)
  const int gl = lane & 7;      // lane within group
  float4 hf[4];
#pragma unroll
  for (int c = 0; c < 4; c++)
    hf[c] = *(const float4*)(h + c * 32 + gl * 4);
  const int wid = blockIdx.x * 4 + (tid >> 6);   // global wave id [0, 8192)
  const int row0 = wid * 32;
#pragma unroll
  for (int it = 0; it < 4; it++) {
    const int row = row0 + it * 8 + g;
    const float* rp = hyp_w2 + (size_t)row * HYP_HID;
    float s = 0.f;
#pragma unroll
    for (int c = 0; c < 4; c++) {
      float4 v = *(const float4*)(rp + c * 32 + gl * 4);
      s += v.x * hf[c].x + v.y * hf[c].y + v.z * hf[c].z + v.w * hf[c].w;
    }
    s += __shfl_xor(s, 4);
    s += __shfl_xor(s, 2);
    s += __shfl_xor(s, 1);
    if (gl == 0) left[row] = s + hyp_b2[row];
  }
}

// ---------------- kernel 3b: W (bf16) = base + left @ lr ----------------
__global__ __launch_bounds__(256) void build_w(
    const float* __restrict__ left, const float* __restrict__ base_w,
    const float* __restrict__ lrf, unsigned short* __restrict__ Wbf) {
  __shared__ float lefts[8][LOW_RANK];
  const int tid = threadIdx.x;
  const int o0 = blockIdx.x * 8;
#pragma unroll
  for (int i = tid; i < 8 * LOW_RANK; i += 256)
    ((float*)lefts)[i] = left[o0 * LOW_RANK + i];
  __syncthreads();

#pragma unroll
  for (int kk = 0; kk < 4; kk++) {
    const int k = kk * 256 + tid;
    float acc[8];
#pragma unroll
    for (int oi = 0; oi < 8; oi++) acc[oi] = base_w[(size_t)(o0 + oi) * MAX_IN + k];
    for (int r = 0; r < LOW_RANK; r++) {
      float lv = lrf[r * MAX_IN + k];
#pragma unroll
      for (int oi = 0; oi < 8; oi++) acc[oi] += lefts[oi][r] * lv;
    }
#pragma unroll
    for (int oi = 0; oi < 8; oi++)
      Wbf[(size_t)(o0 + oi) * MAX_IN + k] = f2bf(acc[oi]);
  }
}

// ---------------- kernel 4: pipelined GEMM  C = Xbf @ Wbf^T + bias ----------------
// 256x256 tile, BK=32, 8 waves (2M x 4N), wave tile 128x64 (8x4 frags of 16x16x32).
// 3 LDS buffers (96 KB), prefetch distance 2, counted vmcnt(4), raw s_barrier.
// LDS swizzle (paired-row): logical (r, chunk c in 0..3) stored at 16B-chunk
//   line=r>>1, chunk'=((r&1)*4+c)^(line&7)  -> 0-conflict ds_read_b128.
// Staged via pre-swizzled GLOBAL source + linear gload_lds dest (rule #21).
__global__ __launch_bounds__(512, 2) void gemm_kernel(
    const unsigned short* __restrict__ A,   // [M][K] bf16
    const unsigned short* __restrict__ B,   // [N][K] bf16 (= W)
    const float* __restrict__ bias,         // [N]
    float* __restrict__ C) {                // [M][N] fp32
  constexpr int K = MAX_IN;
  constexpr int N = MAX_OUT;
  constexpr int TILE = 16384;              // ushorts per buffer (A 8192 + B 8192)
  constexpr int BOFF = 8192;               // B offset (ushorts)
  constexpr int NT = K / 32;               // 32 K-tiles
  __shared__ __align__(16) unsigned short lds[3 * TILE];  // 96 KB

  const int tid = threadIdx.x;             // 0..511
  const int lane = tid & 63;
  const int w = tid >> 6;                  // wave 0..7
  const int wm = w >> 2, wn = w & 3;       // 2M x 4N
  const int fl = lane & 15, hi = lane >> 4;

  // XCD-aware macro-tile swizzle: 512 wgs, XCD x gets an 8x8 macro-tile
  const int orig = blockIdx.x;
  const int macro = orig & 7;              // = XCD
  const int j = orig >> 3;                 // 0..63
  const int bm = ((macro >> 1) * 8 + (j >> 3)) * 256;   // 32 M-tiles
  const int bn = ((macro & 1) * 8 + (j & 7)) * 256;     // 16 N-tiles

  // ---- staging slot -> global (r,c) inverse-swizzle map ----
  // slot s: line=s>>3, u=(s&7)^(line&7), r=2*line+(u>>2), c=u&3
  int r0, c0, r1, c1;
  {
    int s = tid;       int ln = s >> 3; int u = (s & 7) ^ (ln & 7);
    r0 = 2 * ln + (u >> 2); c0 = u & 3;
    s = tid + 512;     ln = s >> 3;     u = (s & 7) ^ (ln & 7);
    r1 = 2 * ln + (u >> 2); c1 = u & 3;
  }
  const unsigned short* Ag0 = A + (size_t)(bm + r0) * K + c0 * 8;
  const unsigned short* Ag1 = A + (size_t)(bm + r1) * K + c1 * 8;
  const unsigned short* Bg0 = B + (size_t)(bn + r0) * K + c0 * 8;
  const unsigned short* Bg1 = B + (size_t)(bn + r1) * K + c1 * 8;

  // ---- fragment read offsets (ushorts, within buffer) ----
  int aoff[8], boff[4];
#pragma unroll
  for (int m = 0; m < 8; m++) {
    const int r = wm * 128 + m * 16 + fl;
    aoff[m] = (r >> 1) * 64 + (((((r & 1) << 2) | hi) ^ ((r >> 1) & 7)) * 8);
  }
#pragma unroll
  for (int n = 0; n < 4; n++) {
    const int r = wn * 64 + n * 16 + fl;
    boff[n] = BOFF + (r >> 1) * 64 + (((((r & 1) << 2) | hi) ^ ((r >> 1) & 7)) * 8);
  }

  f32x4 acc[8][4];
#pragma unroll
  for (int m = 0; m < 8; m++)
#pragma unroll
    for (int n = 0; n < 4; n++) acc[m][n] = (f32x4){0.f, 0.f, 0.f, 0.f};

#define STAGE(p, kt)                                         \
  do {                                                       \
    unsigned short* lb_ = &lds[(p) * TILE];                  \
    gload16(Ag0 + (kt) * 32, &lb_[tid * 8]);                 \
    gload16(Ag1 + (kt) * 32, &lb_[(tid + 512) * 8]);         \
    gload16(Bg0 + (kt) * 32, &lb_[BOFF + tid * 8]);          \
    gload16(Bg1 + (kt) * 32, &lb_[BOFF + (tid + 512) * 8]);  \
  } while (0)

  // prologue: tiles 0,1 in flight; wait tile 0 (tile 1's 4 loads may remain)
  STAGE(0, 0);
  STAGE(1, 1);
  asm volatile("s_waitcnt vmcnt(4)" ::: "memory");
  __builtin_amdgcn_s_barrier();
  __builtin_amdgcn_sched_barrier(0);

  int p = 0;
  for (int kt = 0; kt < NT; ++kt) {
    if (kt + 2 < NT) {
      const int pn = (p + 2 >= 3) ? p - 1 : p + 2;
      STAGE(pn, kt + 2);
    }
    const unsigned short* lb = &lds[p * TILE];
    short8 a[8], b[4];
#pragma unroll
    for (int m = 0; m < 8; m++) a[m] = *(const short8*)&lb[aoff[m]];
#pragma unroll
    for (int n = 0; n < 4; n++) b[n] = *(const short8*)&lb[boff[n]];
    __builtin_amdgcn_s_setprio(1);
#pragma unroll
    for (int m = 0; m < 8; m++)
#pragma unroll
      for (int n = 0; n < 4; n++)
        acc[m][n] = __builtin_amdgcn_mfma_f32_16x16x32_bf16(a[m], b[n], acc[m][n], 0, 0, 0);
    __builtin_amdgcn_s_setprio(0);
    if (kt + 2 < NT) {
      asm volatile("s_waitcnt vmcnt(4)" ::: "memory");   // tile kt+1 landed
    } else if (kt + 2 == NT) {
      asm volatile("s_waitcnt vmcnt(0)" ::: "memory");   // final tile landed
    }
    if (kt + 1 < NT) {
      __builtin_amdgcn_s_barrier();
      __builtin_amdgcn_sched_barrier(0);
    }
    p = (p + 1 == 3) ? 0 : p + 1;
  }
#undef STAGE

  // ---- epilogue: C/D layout col=lane&15, row=(lane>>4)*4+j ----
  float bv[4];
#pragma unroll
  for (int n = 0; n < 4; n++) bv[n] = bias[bn + wn * 64 + n * 16 + fl];
#pragma unroll
  for (int m = 0; m < 8; m++) {
    const int gr0 = bm + wm * 128 + m * 16 + hi * 4;
#pragma unroll
    for (int n = 0; n < 4; n++) {
      const int gc = bn + wn * 64 + n * 16 + fl;
#pragma unroll
      for (int jj = 0; jj < 4; jj++)
        C[(size_t)(gr0 + jj) * N + gc] = acc[m][n][jj] + bv[n];
    }
  }
}

// ---------------- launcher ----------------
extern "C" void kernel_launch(void* const* d_in, const int* in_sizes, int n_in,
                              void* d_out, int out_size, void* d_ws, size_t ws_size,
                              hipStream_t stream) {
  const float* x      = (const float*)d_in[0];
  const float* embed  = (const float*)d_in[1];
  const float* base_w = (const float*)d_in[2];
  const float* base_b = (const float*)d_in[3];
  const float* lrf    = (const float*)d_in[4];
  const float* w1     = (const float*)d_in[5];
  const float* b1     = (const float*)d_in[6];
  const float* w2     = (const float*)d_in[7];
  const float* b2     = (const float*)d_in[8];
  float* out = (float*)d_out;

  char* ws = (char*)d_ws;
  float* h = (float*)ws;                                                  // 512 B
  unsigned short* Xbf = (unsigned short*)(ws + 1024);                     // 16 MB
  size_t off_w = 1024 + (size_t)BATCH_M * MAX_IN * 2;
  unsigned short* Wbf = (unsigned short*)(ws + off_w);                    // 8 MB
  size_t off_left = off_w + (size_t)MAX_OUT * MAX_IN * 2;
  size_t need = off_left + (size_t)MAX_OUT * LOW_RANK * 4;                // +1 MB
  float* left = (ws_size >= need)
      ? (float*)(ws + off_left)
      : out + ((size_t)BATCH_M * MAX_OUT - (size_t)MAX_OUT * LOW_RANK);

  hipLaunchKernelGGL(hyp_kernel, dim3(1), dim3(HYP_HID), 0, stream, w1, b1, embed, h);
  hipLaunchKernelGGL(convert_x, dim3(BATCH_M * MAX_IN / 1024), dim3(256), 0, stream, x, Xbf);
  hipLaunchKernelGGL(build_left, dim3(MAX_OUT * LOW_RANK / 128), dim3(256), 0, stream,
                     w2, b2, h, left);
  hipLaunchKernelGGL(build_w, dim3(MAX_OUT / 8), dim3(256), 0, stream,
                     left, base_w, lrf, Wbf);
  hipLaunchKernelGGL(gemm_kernel, dim3((BATCH_M / 256) * (MAX_OUT / 256)), dim3(512), 0, stream,
                     Xbf, Wbf, base_b, out);
}

// Round 6
// 158.531 us; speedup vs baseline: 1.6703x; 1.0031x over previous
//
#include <hip/hip_runtime.h>

// ---------------- problem constants ----------------
#define MAX_IN   1024
#define MAX_OUT  4096
#define LOW_RANK 64
#define N_ARCH   16
#define HYP_HID  128
#define BATCH_M  8192   // 4 * 2048

typedef __attribute__((ext_vector_type(8))) short short8;   // 8 x bf16
typedef __attribute__((ext_vector_type(4))) float f32x4;

// round-to-nearest-even fp32 -> bf16
__device__ __forceinline__ unsigned short f2bf(float f) {
  union { float f; unsigned int u; } c; c.f = f;
  unsigned int r = c.u + 0x7fffu + ((c.u >> 16) & 1u);
  return (unsigned short)(r >> 16);
}

__device__ __forceinline__ void gload16(const unsigned short* g, unsigned short* l) {
  __builtin_amdgcn_global_load_lds(
      (const __attribute__((address_space(1))) unsigned int*)(g),
      (__attribute__((address_space(3))) unsigned int*)(l), 16, 0, 0);
}

// ---------------- kernel 1: hypernet layer 1 ----------------
__global__ void hyp_kernel(const float* __restrict__ w1, const float* __restrict__ b1,
                           const float* __restrict__ e, float* __restrict__ h) {
  int i = threadIdx.x;  // 128 threads
  float s = b1[i];
#pragma unroll
  for (int j = 0; j < N_ARCH; j++) s += w1[i * N_ARCH + j] * e[j];
  h[i] = fmaxf(s, 0.0f);
}

// ---------------- kernel 2: X fp32 -> bf16 ----------------
__global__ __launch_bounds__(256) void convert_x(const float* __restrict__ in,
                                                 unsigned short* __restrict__ out) {
  size_t i = (size_t)blockIdx.x * 256 + threadIdx.x;
  float4 v = *(const float4*)(in + i * 4);
  ushort4 o;
  o.x = f2bf(v.x); o.y = f2bf(v.y); o.z = f2bf(v.z); o.w = f2bf(v.w);
  *(ushort4*)(out + i * 4) = o;
}

// ---------------- kernel 3a: left = hyp_w2 @ h + b2  (BW-bound matvec) ----------------
__global__ __launch_bounds__(256) void build_left(
    const float* __restrict__ hyp_w2, const float* __restrict__ hyp_b2,
    const float* __restrict__ h, float* __restrict__ left) {
  const int tid = threadIdx.x;
  const int lane = tid & 63;
  const int g = lane >> 3;      // group 0..7 (row within 8-row pack)
  const int gl = lane & 7;      // lane within group
  float4 hf[4];
#pragma unroll
  for (int c = 0; c < 4; c++)
    hf[c] = *(const float4*)(h + c * 32 + gl * 4);
  const int wid = blockIdx.x * 4 + (tid >> 6);   // global wave id [0, 8192)
  const int row0 = wid * 32;
#pragma unroll
  for (int it = 0; it < 4; it++) {
    const int row = row0 + it * 8 + g;
    const float* rp = hyp_w2 + (size_t)row * HYP_HID;
    float s = 0.f;
#pragma unroll
    for (int c = 0; c < 4; c++) {
      float4 v = *(const float4*)(rp + c * 32 + gl * 4);
      s += v.x * hf[c].x + v.y * hf[c].y + v.z * hf[c].z + v.w * hf[c].w;
    }
    s += __shfl_xor(s, 4);
    s += __shfl_xor(s, 2);
    s += __shfl_xor(s, 1);
    if (gl == 0) left[row] = s + hyp_b2[row];
  }
}

// ---------------- kernel 3b: W (bf16) = base + left @ lr ----------------
__global__ __launch_bounds__(256) void build_w(
    const float* __restrict__ left, const float* __restrict__ base_w,
    const float* __restrict__ lrf, unsigned short* __restrict__ Wbf) {
  __shared__ float lefts[8][LOW_RANK];
  const int tid = threadIdx.x;
  const int o0 = blockIdx.x * 8;
#pragma unroll
  for (int i = tid; i < 8 * LOW_RANK; i += 256)
    ((float*)lefts)[i] = left[o0 * LOW_RANK + i];
  __syncthreads();

#pragma unroll
  for (int kk = 0; kk < 4; kk++) {
    const int k = kk * 256 + tid;
    float acc[8];
#pragma unroll
    for (int oi = 0; oi < 8; oi++) acc[oi] = base_w[(size_t)(o0 + oi) * MAX_IN + k];
    for (int r = 0; r < LOW_RANK; r++) {
      float lv = lrf[r * MAX_IN + k];
#pragma unroll
      for (int oi = 0; oi < 8; oi++) acc[oi] += lefts[oi][r] * lv;
    }
#pragma unroll
    for (int oi = 0; oi < 8; oi++)
      Wbf[(size_t)(o0 + oi) * MAX_IN + k] = f2bf(acc[oi]);
  }
}

// ---------------- kernel 4: phase-split pipelined GEMM ----------------
// 256x256 tile, BK=64, NT=16 iters, 8 waves (2M x 4N), wave tile 128x64.
// 4 phases/iter = C-quadrant (qm,qn) 64x32 x K=64 = 16 MFMA of 16x16x32.
// 2 LDS buffers (128 KB). Stage stagger per phase: {A0A2, B0B1, B2B3, A1A3}
// (2 gload_lds each) -> waits vmcnt(4) mid-iter, vmcnt(2) iter-end (never 0).
// Swizzle: 64-col rows (8 x 16B chunks), chunk' = c ^ (r&7); staged via
// inverse-swizzled GLOBAL source + linear gload_lds dest (rule #21).
__global__ __launch_bounds__(512, 2) void gemm_kernel(
    const unsigned short* __restrict__ A,   // [M][K] bf16
    const unsigned short* __restrict__ B,   // [N][K] bf16 (= W)
    const float* __restrict__ bias,         // [N]
    float* __restrict__ C) {                // [M][N] fp32
  constexpr int K = MAX_IN;
  constexpr int N = MAX_OUT;
  constexpr int TILE = 32768;              // ushorts per buffer (A 16384 + B 16384)
  constexpr int BOFF = 16384;
  constexpr int NT = K / 64;               // 16
  __shared__ __align__(16) unsigned short lds[2 * TILE];  // 128 KB

  const int tid = threadIdx.x;             // 0..511
  const int lane = tid & 63;
  const int w = tid >> 6;                  // wave 0..7
  const int wm = w >> 2, wn = w & 3;       // 2M x 4N
  const int fl = lane & 15, hi = lane >> 4;

  // XCD-aware macro-tile swizzle: 512 wgs, XCD x gets an 8x8 macro-tile
  const int orig = blockIdx.x;
  const int macro = orig & 7;
  const int j = orig >> 3;                 // 0..63
  const int bm = ((macro >> 1) * 8 + (j >> 3)) * 256;   // 32 M-tiles
  const int bn = ((macro & 1) * 8 + (j & 7)) * 256;     // 16 N-tiles

  // ---- staging: thread covers row (tid>>3) of each 64-row chunk, slot (tid&7) ----
  // logical chunk c = (tid&7) ^ ((tid>>3)&7)  (j*64 == 0 mod 8 -> same c for all j)
  const int cst = (tid & 7) ^ ((tid >> 3) & 7);
  const unsigned short* Asrc = A + (size_t)(bm + (tid >> 3)) * K + cst * 8;
  const unsigned short* Bsrc = B + (size_t)(bn + (tid >> 3)) * K + cst * 8;

  // ---- fragment read swizzle (r&7 == fl&7 for all frag rows) ----
  const int swz0 = (hi ^ (fl & 7)) * 8;    // kk=0, ushort offset of 16B chunk
  const int swz1 = swz0 ^ 32;              // kk=1 (chunk ^ 4)

  f32x4 acc[8][4];
#pragma unroll
  for (int m = 0; m < 8; m++)
#pragma unroll
    for (int n = 0; n < 4; n++) acc[m][n] = (f32x4){0.f, 0.f, 0.f, 0.f};

  short8 a[4][2], b[2][2];

#define STAGE_A(nb, jj, kt) gload16(Asrc + (size_t)(jj) * 64 * K + (kt) * 64, \
                                    (nb) + ((jj) * 512 + tid) * 8)
#define STAGE_B(nb, jj, kt) gload16(Bsrc + (size_t)(jj) * 64 * K + (kt) * 64, \
                                    (nb) + BOFF + ((jj) * 512 + tid) * 8)
#define READ_A(cb, qm)                                                         \
  _Pragma("unroll") for (int m = 0; m < 4; m++) {                              \
    const int ra = (wm * 128 + (qm) * 64 + m * 16 + fl) * 64;                  \
    a[m][0] = *(const short8*)&(cb)[ra + swz0];                                \
    a[m][1] = *(const short8*)&(cb)[ra + swz1];                                \
  }
#define READ_B(cb, qn)                                                         \
  _Pragma("unroll") for (int n = 0; n < 2; n++) {                              \
    const int rb = BOFF + (wn * 64 + (qn) * 32 + n * 16 + fl) * 64;            \
    b[n][0] = *(const short8*)&(cb)[rb + swz0];                                \
    b[n][1] = *(const short8*)&(cb)[rb + swz1];                                \
  }
#define MFMA16(qm, qn)                                                         \
  __builtin_amdgcn_s_setprio(1);                                               \
  _Pragma("unroll") for (int m = 0; m < 4; m++)                                \
  _Pragma("unroll") for (int n = 0; n < 2; n++)                                \
  _Pragma("unroll") for (int kk = 0; kk < 2; kk++)                             \
    acc[(qm) * 4 + m][(qn) * 2 + n] = __builtin_amdgcn_mfma_f32_16x16x32_bf16( \
        a[m][kk], b[n][kk], acc[(qm) * 4 + m][(qn) * 2 + n], 0, 0, 0);         \
  __builtin_amdgcn_s_setprio(0);
#define BAR() __builtin_amdgcn_s_barrier(); __builtin_amdgcn_sched_barrier(0)

  // prologue: stage tile 0 fully, drain, sync
  {
    unsigned short* nb = lds;
#pragma unroll
    for (int jj = 0; jj < 4; jj++) { STAGE_A(nb, jj, 0); STAGE_B(nb, jj, 0); }
  }
  asm volatile("s_waitcnt vmcnt(0)" ::: "memory");
  BAR();

  for (int t = 0; t < NT; ++t) {
    const unsigned short* cb = &lds[(t & 1) * TILE];
    unsigned short* nb = &lds[((t + 1) & 1) * TILE];
    const bool st = (t + 1 < NT);
    const int kt = t + 1;
    // ---- phase 0: (qm0,qn0) ----
    READ_A(cb, 0); READ_B(cb, 0);
    if (st) { STAGE_A(nb, 0, kt); STAGE_A(nb, 2, kt); }
    MFMA16(0, 0);
    BAR();
    // ---- phase 1: (qm0,qn1) ----
    READ_B(cb, 1);
    if (st) { STAGE_B(nb, 0, kt); STAGE_B(nb, 1, kt); }
    MFMA16(0, 1);
    // need A1,A3 of tile t landed (issued iter t-1 ph3); newest 4 may fly
    if (st) { asm volatile("s_waitcnt vmcnt(4)" ::: "memory"); }
    else    { asm volatile("s_waitcnt vmcnt(0)" ::: "memory"); }
    BAR();
    // ---- phase 2: (qm1,qn0) ----
    READ_A(cb, 1); READ_B(cb, 0);
    if (st) { STAGE_B(nb, 2, kt); STAGE_B(nb, 3, kt); }
    MFMA16(1, 0);
    BAR();
    // ---- phase 3: (qm1,qn1) ----
    READ_B(cb, 1);
    if (st) { STAGE_A(nb, 1, kt); STAGE_A(nb, 3, kt); }
    MFMA16(1, 1);
    if (st) {
      // need tile t+1's A0,A2,B0..B3 landed; allow A1,A3 (newest 2) in flight
      asm volatile("s_waitcnt vmcnt(2)" ::: "memory");
      BAR();
    }
  }
#undef STAGE_A
#undef STAGE_B
#undef READ_A
#undef READ_B
#undef MFMA16
#undef BAR

  // ---- epilogue: C/D layout col=lane&15, row=(lane>>4)*4+j ----
  float bv[4];
#pragma unroll
  for (int n = 0; n < 4; n++) bv[n] = bias[bn + wn * 64 + n * 16 + fl];
#pragma unroll
  for (int m = 0; m < 8; m++) {
    const int gr0 = bm + wm * 128 + m * 16 + hi * 4;
#pragma unroll
    for (int n = 0; n < 4; n++) {
      const int gc = bn + wn * 64 + n * 16 + fl;
#pragma unroll
      for (int jj = 0; jj < 4; jj++)
        C[(size_t)(gr0 + jj) * N + gc] = acc[m][n][jj] + bv[n];
    }
  }
}

// ---------------- launcher ----------------
extern "C" void kernel_launch(void* const* d_in, const int* in_sizes, int n_in,
                              void* d_out, int out_size, void* d_ws, size_t ws_size,
                              hipStream_t stream) {
  const float* x      = (const float*)d_in[0];
  const float* embed  = (const float*)d_in[1];
  const float* base_w = (const float*)d_in[2];
  const float* base_b = (const float*)d_in[3];
  const float* lrf    = (const float*)d_in[4];
  const float* w1     = (const float*)d_in[5];
  const float* b1     = (const float*)d_in[6];
  const float* w2     = (const float*)d_in[7];
  const float* b2     = (const float*)d_in[8];
  float* out = (float*)d_out;

  char* ws = (char*)d_ws;
  float* h = (float*)ws;                                                  // 512 B
  unsigned short* Xbf = (unsigned short*)(ws + 1024);                     // 16 MB
  size_t off_w = 1024 + (size_t)BATCH_M * MAX_IN * 2;
  unsigned short* Wbf = (unsigned short*)(ws + off_w);                    // 8 MB
  size_t off_left = off_w + (size_t)MAX_OUT * MAX_IN * 2;
  size_t need = off_left + (size_t)MAX_OUT * LOW_RANK * 4;                // +1 MB
  float* left = (ws_size >= need)
      ? (float*)(ws + off_left)
      : out + ((size_t)BATCH_M * MAX_OUT - (size_t)MAX_OUT * LOW_RANK);

  hipLaunchKernelGGL(hyp_kernel, dim3(1), dim3(HYP_HID), 0, stream, w1, b1, embed, h);
  hipLaunchKernelGGL(convert_x, dim3(BATCH_M * MAX_IN / 1024), dim3(256), 0, stream, x, Xbf);
  hipLaunchKernelGGL(build_left, dim3(MAX_OUT * LOW_RANK / 128), dim3(256), 0, stream,
                     w2, b2, h, left);
  hipLaunchKernelGGL(build_w, dim3(MAX_OUT / 8), dim3(256), 0, stream,
                     left, base_w, lrf, Wbf);
  hipLaunchKernelGGL(gemm_kernel, dim3((BATCH_M / 256) * (MAX_OUT / 256)), dim3(512), 0, stream,
                     Xbf, Wbf, base_b, out);
}